// Round 5
// baseline (815.791 us; speedup 1.0000x reference)
//
#include <hip/hip_runtime.h>

// SinkhornOT, split-kernel version for MI355X (gfx950).
// Kernel A (gemm_cdist): 1 block = 4 consecutive batch elems (grid-stride),
//   512 thr, 33KB LDS, 6 barriers/problem, register prefetch of next X
//   (issued after Q-epilogue, consumed next loop top -> HBM latency hidden
//   under cdist+C-write). Per problem:
//   X=[q;r] (64x256) -> bf16 fragment-major LDS (single in-place buffer)
//   -> H=relu(X@W1+b1) (MFMA, in-place) -> Q=H@W2+b2 (in-place)
//   -> C via MFMA: C^2 = nq + nr - 2 q.r  (waves 0-3 dot tiles, waves 4-7 norms)
// Kernel B (sinkhorn_mesh, 1 wave = 1 problem, no barriers, wave-sync LDS):
//   15 log-domain Sinkhorn iters + T + 3 mesh iters + cost/sim + T out.
// prep_w packs W1/W2 as bf16 MFMA B-fragments (k-map k_local = 8g+j, used
// consistently for A and B so the bijection cancels; HW-validated r1-r4).

typedef unsigned short u16;
typedef short short8 __attribute__((ext_vector_type(8)));
typedef float f32x4  __attribute__((ext_vector_type(4)));

#define MFMA(a, b, c) __builtin_amdgcn_mfma_f32_16x16x32_bf16((a), (b), (c), 0, 0, 0)

static __device__ __forceinline__ u16 f2bf(float f) {  // RNE float->bf16 (finite)
  unsigned u = __float_as_uint(f);
  return (u16)((u + 0x7FFFu + ((u >> 16) & 1u)) >> 16);
}
static __device__ __forceinline__ float bf2f(u16 h) {
  return __uint_as_float(((unsigned)h) << 16);
}

// ---------------- W fragment prep ----------------
// lane l = g*16 + (n&15) holds B[k = ki*32 + 8g + j][col = 16*ctg + (n&15)]
// ws u16 layout: mat*65536 + ((ki*16 + ctg)*64 + lane)*8 + j   (256 KB total)
__global__ __launch_bounds__(256) void prep_w(const float* __restrict__ W1,
                                              const float* __restrict__ W2,
                                              u16* __restrict__ ws) {
  int id = blockIdx.x * 256 + threadIdx.x;  // 0..131071
  int mat = id >> 16;
  int e = id & 65535;   // e = k*256 + n
  int k = e >> 8, n = e & 255;
  float wv = (mat ? W2 : W1)[e];
  int ki = k >> 5, kl = k & 31;
  int g = kl >> 3, j = kl & 7;
  int lane = g * 16 + (n & 15);
  int ctg = n >> 4;
  ws[mat * 65536 + ((((ki * 16 + ctg) * 64 + lane) << 3) | j)] = f2bf(wv);
}

// ---------------- kernel A ----------------
struct __align__(16) SMemA {
  u16 F[16384];    // 32KB single buffer: X frags -> H frags -> Q frags (in place)
  float nrm[64];   // row norms of Q (0-31 q, 32-63 r)
};

// 64x256 @ 256x256: A fragment-major [ki*4+rt][lane][8] (contiguous b128/lane),
// B fragments from global ws. Wave w owns output cols [32w, 32w+32).
static __device__ __forceinline__ void gemm_frag(const u16* __restrict__ Af,
                                                 const u16* __restrict__ wf,
                                                 int w, int lane, f32x4 acc[4][2]) {
#pragma unroll
  for (int rt = 0; rt < 4; ++rt) {
    acc[rt][0] = f32x4{0.f, 0.f, 0.f, 0.f};
    acc[rt][1] = f32x4{0.f, 0.f, 0.f, 0.f};
  }
  __builtin_amdgcn_s_setprio(1);
#pragma unroll
  for (int ki = 0; ki < 8; ++ki) {
    const u16* bp = wf + (((ki * 16 + 2 * w) * 64 + lane) << 3);
    short8 b0 = *reinterpret_cast<const short8*>(bp);        // 16B/lane, coalesced
    short8 b1 = *reinterpret_cast<const short8*>(bp + 512);  // ct=1 record
    short8 a[4];
#pragma unroll
    for (int rt = 0; rt < 4; ++rt)
      a[rt] = *reinterpret_cast<const short8*>(Af + (((ki * 4 + rt) * 64 + lane) << 3));
#pragma unroll
    for (int rt = 0; rt < 4; ++rt) {
      acc[rt][0] = MFMA(a[rt], b0, acc[rt][0]);
      acc[rt][1] = MFMA(a[rt], b1, acc[rt][1]);
    }
  }
  __builtin_amdgcn_s_setprio(0);
}

__global__ __launch_bounds__(512, 6) void gemm_cdist(
    const float* __restrict__ slots_q, const float* __restrict__ slots_r,
    const float* __restrict__ b1, const float* __restrict__ b2,
    const u16* __restrict__ ws, float* __restrict__ CO, int Bn) {
  __shared__ SMemA sm;
  const int tid = threadIdx.x;
  const int w = tid >> 6, lane = tid & 63, g = lane >> 4, ln = lane & 15;

  const int pb0 = blockIdx.x * 4;
  if (pb0 >= Bn) return;
  const int npb = (Bn - pb0 < 4) ? (Bn - pb0) : 4;

  // hoisted biases
  const float bv1a = b1[32 * w + ln], bv1b = b1[32 * w + 16 + ln];
  const float bv2a = b2[32 * w + ln], bv2b = b2[32 * w + 16 + ln];

  // per-thread staging geometry: slot s = tid + ii*512 -> (ki,rt,sg,sln)
  const float* sp[4];
#pragma unroll
  for (int ii = 0; ii < 4; ++ii) {
    int s = tid + ii * 512;
    int ki = s >> 8, rt = (s >> 6) & 3, sg = (s >> 4) & 3, sln = s & 15;
    int row = rt * 16 + sln;
    int k0 = ki * 32 + sg * 8;
    sp[ii] = ((row < 32) ? (slots_q + row * 256) : (slots_r + (row - 32) * 256)) +
             (size_t)pb0 * 8192 + k0;
  }

  float4 fl[8];
  // prologue: issue loads for p=0
#pragma unroll
  for (int ii = 0; ii < 4; ++ii) {
    fl[2 * ii]     = *reinterpret_cast<const float4*>(sp[ii]);
    fl[2 * ii + 1] = *reinterpret_cast<const float4*>(sp[ii] + 4);
    sp[ii] += 8192;
  }

  for (int p = 0; p < npb; ++p) {
    // ---- convert prefetched X to bf16 frags, write to F ----
#pragma unroll
    for (int ii = 0; ii < 4; ++ii) {
      short8 o;
      o[0] = (short)f2bf(fl[2 * ii].x);     o[1] = (short)f2bf(fl[2 * ii].y);
      o[2] = (short)f2bf(fl[2 * ii].z);     o[3] = (short)f2bf(fl[2 * ii].w);
      o[4] = (short)f2bf(fl[2 * ii + 1].x); o[5] = (short)f2bf(fl[2 * ii + 1].y);
      o[6] = (short)f2bf(fl[2 * ii + 1].z); o[7] = (short)f2bf(fl[2 * ii + 1].w);
      *reinterpret_cast<short8*>(&sm.F[(tid + ii * 512) << 3]) = o;
    }
    __syncthreads();

    f32x4 acc[4][2];
    // ---- GEMM1: H = relu(X@W1 + b1) ----
    gemm_frag(sm.F, ws, w, lane, acc);
    __syncthreads();  // all X reads complete before overwriting F with H
#pragma unroll
    for (int ct = 0; ct < 2; ++ct) {
      float bv = ct ? bv1b : bv1a;
#pragma unroll
      for (int rt = 0; rt < 4; ++rt)
#pragma unroll
        for (int ri = 0; ri < 4; ++ri) {
          // D layout: row = rt*16 + 4g + ri, col = 32w + 16ct + ln (verified r1)
          int lane2 = (2 * ct + (ln >> 3)) * 16 + 4 * g + ri;
          sm.F[(((w * 4 + rt) * 64 + lane2) << 3) | (ln & 7)] =
              f2bf(fmaxf(acc[rt][ct][ri] + bv, 0.0f));
        }
    }
    __syncthreads();

    // ---- GEMM2: Q = H@W2 + b2 ----
    gemm_frag(sm.F, ws + 65536, w, lane, acc);
    __syncthreads();  // all H reads complete before overwriting F with Q
#pragma unroll
    for (int ct = 0; ct < 2; ++ct) {
      float bv = ct ? bv2b : bv2a;
#pragma unroll
      for (int rt = 0; rt < 4; ++rt)
#pragma unroll
        for (int ri = 0; ri < 4; ++ri) {
          int lane2 = (2 * ct + (ln >> 3)) * 16 + 4 * g + ri;
          sm.F[(((w * 4 + rt) * 64 + lane2) << 3) | (ln & 7)] =
              f2bf(acc[rt][ct][ri] + bv);
        }
    }
    // ---- issue prefetch for next problem (hides HBM under cdist+Cwrite) ----
    if (p + 1 < npb) {
#pragma unroll
      for (int ii = 0; ii < 4; ++ii) {
        fl[2 * ii]     = *reinterpret_cast<const float4*>(sp[ii]);
        fl[2 * ii + 1] = *reinterpret_cast<const float4*>(sp[ii] + 4);
        sp[ii] += 8192;
      }
    }
    __syncthreads();

    // ---- C^2 = nq + nr - 2 q.r : waves 0-3 dot tiles, waves 4-7 norms ----
    f32x4 dacc = f32x4{0.f, 0.f, 0.f, 0.f};
    if (w < 4) {
      const int mt = w >> 1, nt = w & 1;  // q row-tile, r row-tile
      __builtin_amdgcn_s_setprio(1);
#pragma unroll
      for (int ki = 0; ki < 8; ++ki) {
        // A = q rows tile mt; B = r rows tile (2+nt) — A-frag of r IS B-frag of r^T
        short8 aq = *reinterpret_cast<const short8*>(
            &sm.F[(((ki * 4 + mt) * 64 + lane) << 3)]);
        short8 br = *reinterpret_cast<const short8*>(
            &sm.F[(((ki * 4 + 2 + nt) * 64 + lane) << 3)]);
        dacc = MFMA(aq, br, dacc);
      }
      __builtin_amdgcn_s_setprio(0);
    } else {
      const int t = w - 4;  // row-tile t: rows 16t .. 16t+15
      float s = 0.f;
#pragma unroll
      for (int ki = 0; ki < 8; ++ki) {
        short8 v = *reinterpret_cast<const short8*>(
            &sm.F[(((ki * 4 + t) * 64 + lane) << 3)]);
#pragma unroll
        for (int i = 0; i < 8; ++i) {
          float f = bf2f((u16)v[i]);
          s = fmaf(f, f, s);
        }
      }
      s += __shfl_xor(s, 16);  // reduce over k-groups g (same row, diff k slice)
      s += __shfl_xor(s, 32);
      if (lane < 16) sm.nrm[t * 16 + lane] = s;
    }
    __syncthreads();

    if (w < 4) {
      const int mt = w >> 1, nt = w & 1;
      float* Cp = CO + (size_t)(pb0 + p) * 1024;
#pragma unroll
      for (int ri = 0; ri < 4; ++ri) {
        int k = mt * 16 + 4 * g + ri;   // D layout: row = 4g+ri, col = ln
        int m = nt * 16 + ln;
        float sq = sm.nrm[k] + sm.nrm[32 + m] - 2.0f * dacc[ri];
        Cp[k * 32 + m] = sqrtf(fmaxf(sq, 0.0f));
      }
    }
    // no barrier: next loop-top writes touch F only; cdist F-reads were
    // fenced by the barrier above, and C-write reads nrm/global only.
  }
}

// ---------------- kernel B: 1 wave = 1 problem, no barriers ----------------
__global__ __launch_bounds__(256, 4) void sinkhorn_mesh(
    const float* __restrict__ CO, float* __restrict__ simO,
    float* __restrict__ TO, float* __restrict__ costO, int Bn) {
  __shared__ float Wl[4][32 * 33];
  __shared__ float ABl[4][64];
  const int wv = threadIdx.x >> 6, lane = threadIdx.x & 63;
  const int p = blockIdx.x * 4 + wv;
  if (p >= Bn) return;
  const int h = lane >> 5, q = lane & 31;  // q = row k (row ops) / col (col ops)
  float* Wm = Wl[wv];
  float* LA = ABl[wv];
  float* LB = ABl[wv] + 32;
  const float* Cp = CO + (size_t)p * 1024;

  // lane holds row q cols [16h,16h+16) in lkr, col q rows [16h,16h+16) in lkc
  float lkr[16], lkc[16];
#pragma unroll
  for (int jj = 0; jj < 4; ++jj) {
    float4 v = *reinterpret_cast<const float4*>(Cp + q * 32 + h * 16 + jj * 4);
    int base = q * 33 + h * 16 + jj * 4;
    Wm[base + 0] = v.x; Wm[base + 1] = v.y; Wm[base + 2] = v.z; Wm[base + 3] = v.w;
    lkr[jj * 4 + 0] = -20.f * v.x; lkr[jj * 4 + 1] = -20.f * v.y;
    lkr[jj * 4 + 2] = -20.f * v.z; lkr[jj * 4 + 3] = -20.f * v.w;
  }
  LB[q] = 0.0f;
  __builtin_amdgcn_wave_barrier();
#pragma unroll
  for (int j = 0; j < 16; ++j) lkc[j] = -20.f * Wm[(h * 16 + j) * 33 + q];

  for (int it = 0; it < 15; ++it) {
    float v[16], mx, s;
#pragma unroll
    for (int j = 0; j < 16; ++j) v[j] = lkr[j] + LB[h * 16 + j];
    mx = v[0];
#pragma unroll
    for (int j = 1; j < 16; ++j) mx = fmaxf(mx, v[j]);
    mx = fmaxf(mx, __shfl_xor(mx, 32));
    s = 0.f;
#pragma unroll
    for (int j = 0; j < 16; ++j) s += __expf(v[j] - mx);
    s += __shfl_xor(s, 32);
    LA[q] = -(mx + __logf(s));  // both halves write identical value
    __builtin_amdgcn_wave_barrier();
#pragma unroll
    for (int j = 0; j < 16; ++j) v[j] = lkc[j] + LA[h * 16 + j];
    mx = v[0];
#pragma unroll
    for (int j = 1; j < 16; ++j) mx = fmaxf(mx, v[j]);
    mx = fmaxf(mx, __shfl_xor(mx, 32));
    s = 0.f;
#pragma unroll
    for (int j = 0; j < 16; ++j) s += __expf(v[j] - mx);
    s += __shfl_xor(s, 32);
    LB[q] = -(mx + __logf(s));
    __builtin_amdgcn_wave_barrier();
  }

  // T = exp(log_K + la + lb), row view
  float t[16];
  {
    float la = LA[q];
#pragma unroll
    for (int j = 0; j < 16; ++j) t[j] = __expf(lkr[j] + la + LB[h * 16 + j]);
  }

  // mesh: T=T^2; row-norm; col-norm (via LDS transpose; wave-sync only)
  for (int mi = 0; mi < 3; ++mi) {
    float s = 0.f;
#pragma unroll
    for (int j = 0; j < 16; ++j) { t[j] *= t[j]; s += t[j]; }
    s += __shfl_xor(s, 32);
    float inv = 1.0f / (s + 1e-8f);
#pragma unroll
    for (int j = 0; j < 16; ++j) Wm[q * 33 + h * 16 + j] = t[j] * inv;
    __builtin_amdgcn_wave_barrier();
#pragma unroll
    for (int j = 0; j < 16; ++j) t[j] = Wm[(h * 16 + j) * 33 + q];  // col view
    s = 0.f;
#pragma unroll
    for (int j = 0; j < 16; ++j) s += t[j];
    s += __shfl_xor(s, 32);
    inv = 1.0f / (s + 1e-8f);
#pragma unroll
    for (int j = 0; j < 16; ++j) Wm[(h * 16 + j) * 33 + q] = t[j] * inv;
    __builtin_amdgcn_wave_barrier();
#pragma unroll
    for (int j = 0; j < 16; ++j) t[j] = Wm[q * 33 + h * 16 + j];  // back to rows
  }

  // cost = sum(T*C); C = -lkr/20
  float pp = 0.f;
#pragma unroll
  for (int j = 0; j < 16; ++j) pp = fmaf(t[j], -0.05f * lkr[j], pp);
  pp += __shfl_xor(pp, 1); pp += __shfl_xor(pp, 2); pp += __shfl_xor(pp, 4);
  pp += __shfl_xor(pp, 8); pp += __shfl_xor(pp, 16); pp += __shfl_xor(pp, 32);
  if (lane == 0) {
    costO[p] = pp;
    simO[p] = 1.0f / (1.0f + __expf(pp));  // sigmoid(-cost)
  }
  // T out (coalesced float4 from row view)
#pragma unroll
  for (int jj = 0; jj < 4; ++jj) {
    float4 o;
    o.x = t[jj * 4 + 0]; o.y = t[jj * 4 + 1];
    o.z = t[jj * 4 + 2]; o.w = t[jj * 4 + 3];
    *reinterpret_cast<float4*>(TO + (size_t)p * 1024 + q * 32 + h * 16 + jj * 4) = o;
  }
}

extern "C" void kernel_launch(void* const* d_in, const int* in_sizes, int n_in,
                              void* d_out, int out_size, void* d_ws, size_t ws_size,
                              hipStream_t stream) {
  const float* slots_q = (const float*)d_in[0];
  const float* slots_r = (const float*)d_in[1];
  const float* W1 = (const float*)d_in[2];
  const float* b1 = (const float*)d_in[3];
  const float* W2 = (const float*)d_in[4];
  const float* b2 = (const float*)d_in[5];
  float* out = (float*)d_out;

  const int Bn = in_sizes[0] / 8192;  // 32*256 per batch element
  u16* ws = (u16*)d_ws;               // 256 KB W fragments

  prep_w<<<dim3(512), dim3(256), 0, stream>>>(W1, W2, ws);

  float* simO = out;
  float* TO = out + Bn;
  float* CO = TO + (size_t)Bn * 1024;
  float* costO = CO + (size_t)Bn * 1024;

  gemm_cdist<<<dim3((Bn + 3) / 4), dim3(512), 0, stream>>>(slots_q, slots_r,
                                                           b1, b2, ws, CO, Bn);
  sinkhorn_mesh<<<dim3((Bn + 3) / 4), dim3(256), 0, stream>>>(CO, simO, TO, costO, Bn);
}

// Round 6
// 551.672 us; speedup vs baseline: 1.4788x; 1.4788x over previous
//
#include <hip/hip_runtime.h>

// SinkhornOT, split-kernel version for MI355X (gfx950).
// Kernel A (gemm_cdist): 1 block = 4 consecutive batch elems, 512 thr,
//   double-buffered 2x32KB LDS, 3 barriers/problem, staging for p+1 issued at
//   G2-start (named float4 regs, NO arrays -> no alloca/scratch) and
//   convert+stored during the cdist phase (HBM latency fully hidden).
//   Buffer roles per iter: bufA: X_p -> Q_p -> cdist; bufB: H_p -> X_{p+1}.
// Kernel B (sinkhorn_mesh, 1 wave = 1 problem, no barriers, wave-sync LDS):
//   15 log-domain Sinkhorn iters + T + 3 mesh iters + cost/sim + T out.
// prep_w packs W1/W2 as bf16 MFMA B-fragments (k-map k_local = 8g+j, used
// consistently for A and B so the bijection cancels; HW-validated r1-r5).

typedef unsigned short u16;
typedef short short8 __attribute__((ext_vector_type(8)));
typedef float f32x4  __attribute__((ext_vector_type(4)));

#define MFMA(a, b, c) __builtin_amdgcn_mfma_f32_16x16x32_bf16((a), (b), (c), 0, 0, 0)

static __device__ __forceinline__ u16 f2bf(float f) {  // RNE float->bf16 (finite)
  unsigned u = __float_as_uint(f);
  return (u16)((u + 0x7FFFu + ((u >> 16) & 1u)) >> 16);
}
static __device__ __forceinline__ float bf2f(u16 h) {
  return __uint_as_float(((unsigned)h) << 16);
}
static __device__ __forceinline__ short8 pack8(float4 a, float4 b) {
  short8 o;
  o[0] = (short)f2bf(a.x); o[1] = (short)f2bf(a.y);
  o[2] = (short)f2bf(a.z); o[3] = (short)f2bf(a.w);
  o[4] = (short)f2bf(b.x); o[5] = (short)f2bf(b.y);
  o[6] = (short)f2bf(b.z); o[7] = (short)f2bf(b.w);
  return o;
}

// ---------------- W fragment prep ----------------
// lane l = g*16 + (n&15) holds B[k = ki*32 + 8g + j][col = 16*ctg + (n&15)]
// ws u16 layout: mat*65536 + ((ki*16 + ctg)*64 + lane)*8 + j   (256 KB total)
__global__ __launch_bounds__(256) void prep_w(const float* __restrict__ W1,
                                              const float* __restrict__ W2,
                                              u16* __restrict__ ws) {
  int id = blockIdx.x * 256 + threadIdx.x;  // 0..131071
  int mat = id >> 16;
  int e = id & 65535;   // e = k*256 + n
  int k = e >> 8, n = e & 255;
  float wv = (mat ? W2 : W1)[e];
  int ki = k >> 5, kl = k & 31;
  int g = kl >> 3, j = kl & 7;
  int lane = g * 16 + (n & 15);
  int ctg = n >> 4;
  ws[mat * 65536 + ((((ki * 16 + ctg) * 64 + lane) << 3) | j)] = f2bf(wv);
}

// 64x256 @ 256x256: A fragment-major [ki*4+rt][lane][8] (contiguous b128/lane),
// B fragments from global ws. Wave w owns output cols [32w, 32w+32).
static __device__ __forceinline__ void gemm_frag(const u16* __restrict__ Af,
                                                 const u16* __restrict__ wf,
                                                 int w, int lane, f32x4 acc[4][2]) {
#pragma unroll
  for (int rt = 0; rt < 4; ++rt) {
    acc[rt][0] = f32x4{0.f, 0.f, 0.f, 0.f};
    acc[rt][1] = f32x4{0.f, 0.f, 0.f, 0.f};
  }
  __builtin_amdgcn_s_setprio(1);
#pragma unroll
  for (int ki = 0; ki < 8; ++ki) {
    const u16* bp = wf + (((ki * 16 + 2 * w) * 64 + lane) << 3);
    short8 b0 = *reinterpret_cast<const short8*>(bp);        // 16B/lane, coalesced
    short8 b1 = *reinterpret_cast<const short8*>(bp + 512);  // ct=1 record
    short8 a[4];
#pragma unroll
    for (int rt = 0; rt < 4; ++rt)
      a[rt] = *reinterpret_cast<const short8*>(Af + (((ki * 4 + rt) * 64 + lane) << 3));
#pragma unroll
    for (int rt = 0; rt < 4; ++rt) {
      acc[rt][0] = MFMA(a[rt], b0, acc[rt][0]);
      acc[rt][1] = MFMA(a[rt], b1, acc[rt][1]);
    }
  }
  __builtin_amdgcn_s_setprio(0);
}

__global__ __launch_bounds__(512, 4) void gemm_cdist(
    const float* __restrict__ slots_q, const float* __restrict__ slots_r,
    const float* __restrict__ b1, const float* __restrict__ b2,
    const u16* __restrict__ ws, float* __restrict__ CO, int Bn) {
  __shared__ u16 FA[16384];   // 32KB
  __shared__ u16 FB[16384];   // 32KB
  __shared__ float nrm[64];
  const int tid = threadIdx.x;
  const int w = tid >> 6, lane = tid & 63, g = lane >> 4, ln = lane & 15;

  const int pb0 = blockIdx.x * 4;
  if (pb0 >= Bn) return;
  const int npb = (Bn - pb0 < 4) ? (Bn - pb0) : 4;

  const float bv1a = b1[32 * w + ln], bv1b = b1[32 * w + 16 + ln];
  const float bv2a = b2[32 * w + ln], bv2b = b2[32 * w + 16 + ln];

  // staging geometry, slot s = tid + ii*512 -> (ki,rt,sg,sln); NAMED pointers
  const float *pA, *pB, *pC, *pD;
  {
    int s, ki, rt, sg, sln, row, k0;
#define MKPTR(P, II)                                                         \
    s = tid + (II)*512; ki = s >> 8; rt = (s >> 6) & 3; sg = (s >> 4) & 3;   \
    sln = s & 15; row = rt * 16 + sln; k0 = ki * 32 + sg * 8;                \
    P = ((row < 32) ? (slots_q + row * 256) : (slots_r + (row - 32) * 256)) +\
        (size_t)pb0 * 8192 + k0;
    MKPTR(pA, 0) MKPTR(pB, 1) MKPTR(pC, 2) MKPTR(pD, 3)
#undef MKPTR
  }

  // NAMED prefetch registers (no arrays -> SROA keeps them in VGPRs)
  float4 fA0, fA1, fB0, fB1, fC0, fC1, fD0, fD1;

  // prologue: stage p=0 into FA
  fA0 = *reinterpret_cast<const float4*>(pA); fA1 = *reinterpret_cast<const float4*>(pA + 4);
  fB0 = *reinterpret_cast<const float4*>(pB); fB1 = *reinterpret_cast<const float4*>(pB + 4);
  fC0 = *reinterpret_cast<const float4*>(pC); fC1 = *reinterpret_cast<const float4*>(pC + 4);
  fD0 = *reinterpret_cast<const float4*>(pD); fD1 = *reinterpret_cast<const float4*>(pD + 4);
  pA += 8192; pB += 8192; pC += 8192; pD += 8192;
  *reinterpret_cast<short8*>(&FA[(tid +    0) << 3]) = pack8(fA0, fA1);
  *reinterpret_cast<short8*>(&FA[(tid +  512) << 3]) = pack8(fB0, fB1);
  *reinterpret_cast<short8*>(&FA[(tid + 1024) << 3]) = pack8(fC0, fC1);
  *reinterpret_cast<short8*>(&FA[(tid + 1536) << 3]) = pack8(fD0, fD1);
  __syncthreads();

  u16* bufX = FA;  // holds X_p (then Q_p)
  u16* bufH = FB;  // gets H_p, then X_{p+1}

  for (int p = 0; p < npb; ++p) {
    const bool pf = (p + 1 < npb);
    f32x4 acc[4][2];

    // ---- G1: H = relu(X@W1+b1); MFMA reads bufX, epilogue writes bufH ----
    gemm_frag(bufX, ws, w, lane, acc);
#pragma unroll
    for (int ct = 0; ct < 2; ++ct) {
      float bv = ct ? bv1b : bv1a;
#pragma unroll
      for (int rt = 0; rt < 4; ++rt)
#pragma unroll
        for (int ri = 0; ri < 4; ++ri) {
          // D layout: row = rt*16 + 4g + ri, col = 32w + 16ct + ln (verified r1)
          int lane2 = (2 * ct + (ln >> 3)) * 16 + 4 * g + ri;
          bufH[(((w * 4 + rt) * 64 + lane2) << 3) | (ln & 7)] =
              f2bf(fmaxf(acc[rt][ct][ri] + bv, 0.0f));
        }
    }
    __syncthreads();  // bar1: H complete (X reads also done)

    // ---- issue prefetch loads for p+1 (consumed in cdist phase) ----
    if (pf) {
      fA0 = *reinterpret_cast<const float4*>(pA); fA1 = *reinterpret_cast<const float4*>(pA + 4);
      fB0 = *reinterpret_cast<const float4*>(pB); fB1 = *reinterpret_cast<const float4*>(pB + 4);
      fC0 = *reinterpret_cast<const float4*>(pC); fC1 = *reinterpret_cast<const float4*>(pC + 4);
      fD0 = *reinterpret_cast<const float4*>(pD); fD1 = *reinterpret_cast<const float4*>(pD + 4);
      pA += 8192; pB += 8192; pC += 8192; pD += 8192;
    }

    // ---- G2: Q = H@W2+b2; MFMA reads bufH, epilogue writes bufX (X dead) ----
    gemm_frag(bufH, ws + 65536, w, lane, acc);
#pragma unroll
    for (int ct = 0; ct < 2; ++ct) {
      float bv = ct ? bv2b : bv2a;
#pragma unroll
      for (int rt = 0; rt < 4; ++rt)
#pragma unroll
        for (int ri = 0; ri < 4; ++ri) {
          int lane2 = (2 * ct + (ln >> 3)) * 16 + 4 * g + ri;
          bufX[(((w * 4 + rt) * 64 + lane2) << 3) | (ln & 7)] =
              f2bf(acc[rt][ct][ri] + bv);
        }
    }
    __syncthreads();  // bar2: Q complete (H reads also done)

    // ---- cdist phase: stage X_{p+1} into bufH (H dead); dot/norms on bufX ----
    if (pf) {
      *reinterpret_cast<short8*>(&bufH[(tid +    0) << 3]) = pack8(fA0, fA1);
      *reinterpret_cast<short8*>(&bufH[(tid +  512) << 3]) = pack8(fB0, fB1);
      *reinterpret_cast<short8*>(&bufH[(tid + 1024) << 3]) = pack8(fC0, fC1);
      *reinterpret_cast<short8*>(&bufH[(tid + 1536) << 3]) = pack8(fD0, fD1);
    }
    f32x4 dacc = f32x4{0.f, 0.f, 0.f, 0.f};
    if (w < 4) {
      const int mt = w >> 1, nt = w & 1;  // q row-tile, r row-tile
      __builtin_amdgcn_s_setprio(1);
#pragma unroll
      for (int ki = 0; ki < 8; ++ki) {
        // A = q rows tile mt; B = r rows tile (2+nt) — A-frag of r IS B-frag of r^T
        short8 aq = *reinterpret_cast<const short8*>(
            &bufX[(((ki * 4 + mt) * 64 + lane) << 3)]);
        short8 br = *reinterpret_cast<const short8*>(
            &bufX[(((ki * 4 + 2 + nt) * 64 + lane) << 3)]);
        dacc = MFMA(aq, br, dacc);
      }
      __builtin_amdgcn_s_setprio(0);
    } else {
      const int t = w - 4;  // row-tile t: rows 16t .. 16t+15
      float s = 0.f;
#pragma unroll
      for (int ki = 0; ki < 8; ++ki) {
        short8 v = *reinterpret_cast<const short8*>(
            &bufX[(((ki * 4 + t) * 64 + lane) << 3)]);
#pragma unroll
        for (int i = 0; i < 8; ++i) {
          float f = bf2f((u16)v[i]);
          s = fmaf(f, f, s);
        }
      }
      s += __shfl_xor(s, 16);  // reduce over k-groups g (same row, diff k slice)
      s += __shfl_xor(s, 32);
      if (lane < 16) nrm[t * 16 + lane] = s;
    }
    __syncthreads();  // bar3: cdist reads done, nrm ready, X_{p+1} staged

    if (w < 4) {
      const int mt = w >> 1, nt = w & 1;
      float* Cp = CO + (size_t)(pb0 + p) * 1024;
#pragma unroll
      for (int ri = 0; ri < 4; ++ri) {
        int k = mt * 16 + 4 * g + ri;   // D layout: row = 4g+ri, col = ln
        int m = nt * 16 + ln;
        float sq = nrm[k] + nrm[32 + m] - 2.0f * dacc[ri];
        Cp[k * 32 + m] = sqrtf(fmaxf(sq, 0.0f));
      }
    }
    // swap buffer roles; next iter's writes (H into old bufX) are fenced by
    // bar1 of next iteration relative to any lingering reads (none remain).
    u16* tmp = bufX; bufX = bufH; bufH = tmp;
  }
}

// ---------------- kernel B: 1 wave = 1 problem, no barriers ----------------
__global__ __launch_bounds__(256, 4) void sinkhorn_mesh(
    const float* __restrict__ CO, float* __restrict__ simO,
    float* __restrict__ TO, float* __restrict__ costO, int Bn) {
  __shared__ float Wl[4][32 * 33];
  __shared__ float ABl[4][64];
  const int wv = threadIdx.x >> 6, lane = threadIdx.x & 63;
  const int p = blockIdx.x * 4 + wv;
  if (p >= Bn) return;
  const int h = lane >> 5, q = lane & 31;  // q = row k (row ops) / col (col ops)
  float* Wm = Wl[wv];
  float* LA = ABl[wv];
  float* LB = ABl[wv] + 32;
  const float* Cp = CO + (size_t)p * 1024;

  // lane holds row q cols [16h,16h+16) in lkr, col q rows [16h,16h+16) in lkc
  float lkr[16], lkc[16];
#pragma unroll
  for (int jj = 0; jj < 4; ++jj) {
    float4 v = *reinterpret_cast<const float4*>(Cp + q * 32 + h * 16 + jj * 4);
    int base = q * 33 + h * 16 + jj * 4;
    Wm[base + 0] = v.x; Wm[base + 1] = v.y; Wm[base + 2] = v.z; Wm[base + 3] = v.w;
    lkr[jj * 4 + 0] = -20.f * v.x; lkr[jj * 4 + 1] = -20.f * v.y;
    lkr[jj * 4 + 2] = -20.f * v.z; lkr[jj * 4 + 3] = -20.f * v.w;
  }
  LB[q] = 0.0f;
  __builtin_amdgcn_wave_barrier();
#pragma unroll
  for (int j = 0; j < 16; ++j) lkc[j] = -20.f * Wm[(h * 16 + j) * 33 + q];

  for (int it = 0; it < 15; ++it) {
    float v[16], mx, s;
#pragma unroll
    for (int j = 0; j < 16; ++j) v[j] = lkr[j] + LB[h * 16 + j];
    mx = v[0];
#pragma unroll
    for (int j = 1; j < 16; ++j) mx = fmaxf(mx, v[j]);
    mx = fmaxf(mx, __shfl_xor(mx, 32));
    s = 0.f;
#pragma unroll
    for (int j = 0; j < 16; ++j) s += __expf(v[j] - mx);
    s += __shfl_xor(s, 32);
    LA[q] = -(mx + __logf(s));  // both halves write identical value
    __builtin_amdgcn_wave_barrier();
#pragma unroll
    for (int j = 0; j < 16; ++j) v[j] = lkc[j] + LA[h * 16 + j];
    mx = v[0];
#pragma unroll
    for (int j = 1; j < 16; ++j) mx = fmaxf(mx, v[j]);
    mx = fmaxf(mx, __shfl_xor(mx, 32));
    s = 0.f;
#pragma unroll
    for (int j = 0; j < 16; ++j) s += __expf(v[j] - mx);
    s += __shfl_xor(s, 32);
    LB[q] = -(mx + __logf(s));
    __builtin_amdgcn_wave_barrier();
  }

  // T = exp(log_K + la + lb), row view
  float t[16];
  {
    float la = LA[q];
#pragma unroll
    for (int j = 0; j < 16; ++j) t[j] = __expf(lkr[j] + la + LB[h * 16 + j]);
  }

  // mesh: T=T^2; row-norm; col-norm (via LDS transpose; wave-sync only)
  for (int mi = 0; mi < 3; ++mi) {
    float s = 0.f;
#pragma unroll
    for (int j = 0; j < 16; ++j) { t[j] *= t[j]; s += t[j]; }
    s += __shfl_xor(s, 32);
    float inv = 1.0f / (s + 1e-8f);
#pragma unroll
    for (int j = 0; j < 16; ++j) Wm[q * 33 + h * 16 + j] = t[j] * inv;
    __builtin_amdgcn_wave_barrier();
#pragma unroll
    for (int j = 0; j < 16; ++j) t[j] = Wm[(h * 16 + j) * 33 + q];  // col view
    s = 0.f;
#pragma unroll
    for (int j = 0; j < 16; ++j) s += t[j];
    s += __shfl_xor(s, 32);
    inv = 1.0f / (s + 1e-8f);
#pragma unroll
    for (int j = 0; j < 16; ++j) Wm[(h * 16 + j) * 33 + q] = t[j] * inv;
    __builtin_amdgcn_wave_barrier();
#pragma unroll
    for (int j = 0; j < 16; ++j) t[j] = Wm[q * 33 + h * 16 + j];  // back to rows
  }

  // cost = sum(T*C); C = -lkr/20
  float pp = 0.f;
#pragma unroll
  for (int j = 0; j < 16; ++j) pp = fmaf(t[j], -0.05f * lkr[j], pp);
  pp += __shfl_xor(pp, 1); pp += __shfl_xor(pp, 2); pp += __shfl_xor(pp, 4);
  pp += __shfl_xor(pp, 8); pp += __shfl_xor(pp, 16); pp += __shfl_xor(pp, 32);
  if (lane == 0) {
    costO[p] = pp;
    simO[p] = 1.0f / (1.0f + __expf(pp));  // sigmoid(-cost)
  }
  // T out (coalesced float4 from row view)
#pragma unroll
  for (int jj = 0; jj < 4; ++jj) {
    float4 o;
    o.x = t[jj * 4 + 0]; o.y = t[jj * 4 + 1];
    o.z = t[jj * 4 + 2]; o.w = t[jj * 4 + 3];
    *reinterpret_cast<float4*>(TO + (size_t)p * 1024 + q * 32 + h * 16 + jj * 4) = o;
  }
}

extern "C" void kernel_launch(void* const* d_in, const int* in_sizes, int n_in,
                              void* d_out, int out_size, void* d_ws, size_t ws_size,
                              hipStream_t stream) {
  const float* slots_q = (const float*)d_in[0];
  const float* slots_r = (const float*)d_in[1];
  const float* W1 = (const float*)d_in[2];
  const float* b1 = (const float*)d_in[3];
  const float* W2 = (const float*)d_in[4];
  const float* b2 = (const float*)d_in[5];
  float* out = (float*)d_out;

  const int Bn = in_sizes[0] / 8192;  // 32*256 per batch element
  u16* ws = (u16*)d_ws;               // 256 KB W fragments

  prep_w<<<dim3(512), dim3(256), 0, stream>>>(W1, W2, ws);

  float* simO = out;
  float* TO = out + Bn;
  float* CO = TO + (size_t)Bn * 1024;
  float* costO = CO + (size_t)Bn * 1024;

  gemm_cdist<<<dim3((Bn + 3) / 4), dim3(512), 0, stream>>>(slots_q, slots_r,
                                                           b1, b2, ws, CO, Bn);
  sinkhorn_mesh<<<dim3((Bn + 3) / 4), dim3(256), 0, stream>>>(CO, simO, TO, costO, Bn);
}

// Round 7
// 256.995 us; speedup vs baseline: 3.1743x; 2.1466x over previous
//
#include <hip/hip_runtime.h>
#include <hip/hip_bf16.h>

// SinkhornOT, split-kernel version for MI355X (gfx950).
// Kernel A (gemm_cdist, 1 block = 1 batch elem, 512 thr, 33KB LDS, 6 barriers,
//           4 blocks/CU co-resident; r4 structure = best-known 235us, no spill):
//   X=[q;r] (64x256) -> bf16 fragment-major LDS (single in-place buffer)
//   -> H=relu(X@W1+b1) (MFMA, in-place) -> Q=H@W2+b2 (in-place)
//   -> C via MFMA: C^2 = nq + nr - 2 q.r  (waves 0-3 dot tiles, waves 4-7 norms)
// This round: native __float2bfloat16 (compiler emits v_cvt_pk_bf16_f32) in
// place of the 4-op hand-rolled RNE — cuts ~400 VALU insts/lane.
// LESSON (r5/r6): no HBM prefetch data may be held in VGPRs across a GEMM
// phase — it spills to scratch (WRITE_SIZE 610MB-1GB) at any useful occupancy.
// Kernel B (sinkhorn_mesh, 1 wave = 1 problem, no barriers, wave-sync LDS):
//   15 log-domain Sinkhorn iters + T + 3 mesh iters + cost/sim + T out.
// prep_w packs W1/W2 as bf16 MFMA B-fragments (k-map k_local = 8g+j, used
// consistently for A and B so the bijection cancels; HW-validated r1-r6).

typedef unsigned short u16;
typedef short short8 __attribute__((ext_vector_type(8)));
typedef float f32x4  __attribute__((ext_vector_type(4)));

#define MFMA(a, b, c) __builtin_amdgcn_mfma_f32_16x16x32_bf16((a), (b), (c), 0, 0, 0)

static __device__ __forceinline__ u16 f2bf(float f) {  // native RNE cvt (1 op, pairs fuse to v_cvt_pk_bf16_f32)
  __hip_bfloat16 h = __float2bfloat16(f);
  return __builtin_bit_cast(u16, h);
}
static __device__ __forceinline__ float bf2f(u16 h) {
  return __uint_as_float(((unsigned)h) << 16);
}

// ---------------- W fragment prep ----------------
// lane l = g*16 + (n&15) holds B[k = ki*32 + 8g + j][col = 16*ctg + (n&15)]
// ws u16 layout: mat*65536 + ((ki*16 + ctg)*64 + lane)*8 + j   (256 KB total)
__global__ __launch_bounds__(256) void prep_w(const float* __restrict__ W1,
                                              const float* __restrict__ W2,
                                              u16* __restrict__ ws) {
  int id = blockIdx.x * 256 + threadIdx.x;  // 0..131071
  int mat = id >> 16;
  int e = id & 65535;   // e = k*256 + n
  int k = e >> 8, n = e & 255;
  float wv = (mat ? W2 : W1)[e];
  int ki = k >> 5, kl = k & 31;
  int g = kl >> 3, j = kl & 7;
  int lane = g * 16 + (n & 15);
  int ctg = n >> 4;
  ws[mat * 65536 + ((((ki * 16 + ctg) * 64 + lane) << 3) | j)] = f2bf(wv);
}

// ---------------- kernel A ----------------
struct __align__(16) SMemA {
  u16 F[16384];    // 32KB single buffer: X frags -> H frags -> Q frags (in place)
  float nrm[64];   // row norms of Q (0-31 q, 32-63 r)
};

// 64x256 @ 256x256: A fragment-major [ki*4+rt][lane][8] (contiguous b128/lane),
// B fragments from global ws. Wave w owns output cols [32w, 32w+32).
static __device__ __forceinline__ void gemm_frag(const u16* __restrict__ Af,
                                                 const u16* __restrict__ wf,
                                                 int w, int lane, f32x4 acc[4][2]) {
#pragma unroll
  for (int rt = 0; rt < 4; ++rt) {
    acc[rt][0] = f32x4{0.f, 0.f, 0.f, 0.f};
    acc[rt][1] = f32x4{0.f, 0.f, 0.f, 0.f};
  }
  __builtin_amdgcn_s_setprio(1);
#pragma unroll
  for (int ki = 0; ki < 8; ++ki) {
    const u16* bp = wf + (((ki * 16 + 2 * w) * 64 + lane) << 3);
    short8 b0 = *reinterpret_cast<const short8*>(bp);        // 16B/lane, coalesced
    short8 b1 = *reinterpret_cast<const short8*>(bp + 512);  // ct=1 record
    short8 a[4];
#pragma unroll
    for (int rt = 0; rt < 4; ++rt)
      a[rt] = *reinterpret_cast<const short8*>(Af + (((ki * 4 + rt) * 64 + lane) << 3));
#pragma unroll
    for (int rt = 0; rt < 4; ++rt) {
      acc[rt][0] = MFMA(a[rt], b0, acc[rt][0]);
      acc[rt][1] = MFMA(a[rt], b1, acc[rt][1]);
    }
  }
  __builtin_amdgcn_s_setprio(0);
}

__global__ __launch_bounds__(512, 8) void gemm_cdist(
    const float* __restrict__ slots_q, const float* __restrict__ slots_r,
    const float* __restrict__ b1, const float* __restrict__ b2,
    const u16* __restrict__ ws, float* __restrict__ CO) {
  __shared__ SMemA sm;
  const int tid = threadIdx.x, b = blockIdx.x;
  const int w = tid >> 6, lane = tid & 63, g = lane >> 4, ln = lane & 15;

  // ---- stage X fragment-major: slot s = (ki*4+rt)*64 + g*16 + ln ----
  {
    const float* srcq = slots_q + (size_t)b * 8192;
    const float* srcr = slots_r + (size_t)b * 8192;
#pragma unroll
    for (int ii = 0; ii < 4; ++ii) {
      int s = tid + ii * 512;  // 0..2047
      int ki = s >> 8, rt = (s >> 6) & 3, sg = (s >> 4) & 3, sln = s & 15;
      int row = rt * 16 + sln;
      const float* src = (row < 32) ? (srcq + row * 256) : (srcr + (row - 32) * 256);
      int k0 = ki * 32 + sg * 8;
      float4 v0 = *reinterpret_cast<const float4*>(src + k0);
      float4 v1 = *reinterpret_cast<const float4*>(src + k0 + 4);
      short8 o;
      o[0] = (short)f2bf(v0.x); o[1] = (short)f2bf(v0.y);
      o[2] = (short)f2bf(v0.z); o[3] = (short)f2bf(v0.w);
      o[4] = (short)f2bf(v1.x); o[5] = (short)f2bf(v1.y);
      o[6] = (short)f2bf(v1.z); o[7] = (short)f2bf(v1.w);
      *reinterpret_cast<short8*>(&sm.F[s << 3]) = o;  // contiguous, conflict-free
    }
  }
  float bv1a = b1[32 * w + ln], bv1b = b1[32 * w + 16 + ln];
  float bv2a = b2[32 * w + ln], bv2b = b2[32 * w + 16 + ln];
  __syncthreads();

  f32x4 acc[4][2];
  // ---- GEMM1: H = relu(X@W1 + b1) ----
  gemm_frag(sm.F, ws, w, lane, acc);
  __syncthreads();  // all X reads complete before overwriting F with H
#pragma unroll
  for (int ct = 0; ct < 2; ++ct) {
    float bv = ct ? bv1b : bv1a;
#pragma unroll
    for (int rt = 0; rt < 4; ++rt)
#pragma unroll
      for (int ri = 0; ri < 4; ++ri) {
        // D layout: row = rt*16 + 4g + ri, col = 32w + 16ct + ln (verified r1)
        int lane2 = (2 * ct + (ln >> 3)) * 16 + 4 * g + ri;
        sm.F[(((w * 4 + rt) * 64 + lane2) << 3) | (ln & 7)] =
            f2bf(fmaxf(acc[rt][ct][ri] + bv, 0.0f));
      }
  }
  __syncthreads();

  // ---- GEMM2: Q = H@W2 + b2 ----
  gemm_frag(sm.F, ws + 65536, w, lane, acc);
  __syncthreads();  // all H reads complete before overwriting F with Q
#pragma unroll
  for (int ct = 0; ct < 2; ++ct) {
    float bv = ct ? bv2b : bv2a;
#pragma unroll
    for (int rt = 0; rt < 4; ++rt)
#pragma unroll
      for (int ri = 0; ri < 4; ++ri) {
        int lane2 = (2 * ct + (ln >> 3)) * 16 + 4 * g + ri;
        sm.F[(((w * 4 + rt) * 64 + lane2) << 3) | (ln & 7)] =
            f2bf(acc[rt][ct][ri] + bv);
      }
  }
  __syncthreads();

  // ---- C^2 = nq + nr - 2 q.r : waves 0-3 dot tiles (MFMA), waves 4-7 norms ----
  f32x4 dacc = f32x4{0.f, 0.f, 0.f, 0.f};
  if (w < 4) {
    const int mt = w >> 1, nt = w & 1;  // q row-tile, r row-tile
    __builtin_amdgcn_s_setprio(1);
#pragma unroll
    for (int ki = 0; ki < 8; ++ki) {
      // A = q rows tile mt; B = r rows tile (2+nt) — A-frag of r IS B-frag of r^T
      short8 aq = *reinterpret_cast<const short8*>(
          &sm.F[(((ki * 4 + mt) * 64 + lane) << 3)]);
      short8 br = *reinterpret_cast<const short8*>(
          &sm.F[(((ki * 4 + 2 + nt) * 64 + lane) << 3)]);
      dacc = MFMA(aq, br, dacc);
    }
    __builtin_amdgcn_s_setprio(0);
  } else {
    const int t = w - 4;  // row-tile t: rows 16t .. 16t+15
    float s = 0.f;
#pragma unroll
    for (int ki = 0; ki < 8; ++ki) {
      short8 v = *reinterpret_cast<const short8*>(
          &sm.F[(((ki * 4 + t) * 64 + lane) << 3)]);
#pragma unroll
      for (int i = 0; i < 8; ++i) {
        float f = bf2f((u16)v[i]);
        s = fmaf(f, f, s);
      }
    }
    s += __shfl_xor(s, 16);  // reduce over k-groups g (same row, different k slice)
    s += __shfl_xor(s, 32);
    if (lane < 16) sm.nrm[t * 16 + lane] = s;
  }
  __syncthreads();

  if (w < 4) {
    const int mt = w >> 1, nt = w & 1;
    float* Cp = CO + (size_t)b * 1024;
#pragma unroll
    for (int ri = 0; ri < 4; ++ri) {
      int k = mt * 16 + 4 * g + ri;   // D layout: row = 4g+ri, col = ln
      int m = nt * 16 + ln;
      float sq = sm.nrm[k] + sm.nrm[32 + m] - 2.0f * dacc[ri];
      Cp[k * 32 + m] = sqrtf(fmaxf(sq, 0.0f));
    }
  }
}

// ---------------- kernel B: 1 wave = 1 problem, no barriers ----------------
__global__ __launch_bounds__(256, 4) void sinkhorn_mesh(
    const float* __restrict__ CO, float* __restrict__ simO,
    float* __restrict__ TO, float* __restrict__ costO, int Bn) {
  __shared__ float Wl[4][32 * 33];
  __shared__ float ABl[4][64];
  const int wv = threadIdx.x >> 6, lane = threadIdx.x & 63;
  const int p = blockIdx.x * 4 + wv;
  if (p >= Bn) return;
  const int h = lane >> 5, q = lane & 31;  // q = row k (row ops) / col (col ops)
  float* Wm = Wl[wv];
  float* LA = ABl[wv];
  float* LB = ABl[wv] + 32;
  const float* Cp = CO + (size_t)p * 1024;

  // lane holds row q cols [16h,16h+16) in lkr, col q rows [16h,16h+16) in lkc
  float lkr[16], lkc[16];
#pragma unroll
  for (int jj = 0; jj < 4; ++jj) {
    float4 v = *reinterpret_cast<const float4*>(Cp + q * 32 + h * 16 + jj * 4);
    int base = q * 33 + h * 16 + jj * 4;
    Wm[base + 0] = v.x; Wm[base + 1] = v.y; Wm[base + 2] = v.z; Wm[base + 3] = v.w;
    lkr[jj * 4 + 0] = -20.f * v.x; lkr[jj * 4 + 1] = -20.f * v.y;
    lkr[jj * 4 + 2] = -20.f * v.z; lkr[jj * 4 + 3] = -20.f * v.w;
  }
  LB[q] = 0.0f;
  __builtin_amdgcn_wave_barrier();
#pragma unroll
  for (int j = 0; j < 16; ++j) lkc[j] = -20.f * Wm[(h * 16 + j) * 33 + q];

  for (int it = 0; it < 15; ++it) {
    float v[16], mx, s;
#pragma unroll
    for (int j = 0; j < 16; ++j) v[j] = lkr[j] + LB[h * 16 + j];
    mx = v[0];
#pragma unroll
    for (int j = 1; j < 16; ++j) mx = fmaxf(mx, v[j]);
    mx = fmaxf(mx, __shfl_xor(mx, 32));
    s = 0.f;
#pragma unroll
    for (int j = 0; j < 16; ++j) s += __expf(v[j] - mx);
    s += __shfl_xor(s, 32);
    LA[q] = -(mx + __logf(s));  // both halves write identical value
    __builtin_amdgcn_wave_barrier();
#pragma unroll
    for (int j = 0; j < 16; ++j) v[j] = lkc[j] + LA[h * 16 + j];
    mx = v[0];
#pragma unroll
    for (int j = 1; j < 16; ++j) mx = fmaxf(mx, v[j]);
    mx = fmaxf(mx, __shfl_xor(mx, 32));
    s = 0.f;
#pragma unroll
    for (int j = 0; j < 16; ++j) s += __expf(v[j] - mx);
    s += __shfl_xor(s, 32);
    LB[q] = -(mx + __logf(s));
    __builtin_amdgcn_wave_barrier();
  }

  // T = exp(log_K + la + lb), row view
  float t[16];
  {
    float la = LA[q];
#pragma unroll
    for (int j = 0; j < 16; ++j) t[j] = __expf(lkr[j] + la + LB[h * 16 + j]);
  }

  // mesh: T=T^2; row-norm; col-norm (via LDS transpose; wave-sync only)
  for (int mi = 0; mi < 3; ++mi) {
    float s = 0.f;
#pragma unroll
    for (int j = 0; j < 16; ++j) { t[j] *= t[j]; s += t[j]; }
    s += __shfl_xor(s, 32);
    float inv = 1.0f / (s + 1e-8f);
#pragma unroll
    for (int j = 0; j < 16; ++j) Wm[q * 33 + h * 16 + j] = t[j] * inv;
    __builtin_amdgcn_wave_barrier();
#pragma unroll
    for (int j = 0; j < 16; ++j) t[j] = Wm[(h * 16 + j) * 33 + q];  // col view
    s = 0.f;
#pragma unroll
    for (int j = 0; j < 16; ++j) s += t[j];
    s += __shfl_xor(s, 32);
    inv = 1.0f / (s + 1e-8f);
#pragma unroll
    for (int j = 0; j < 16; ++j) Wm[(h * 16 + j) * 33 + q] = t[j] * inv;
    __builtin_amdgcn_wave_barrier();
#pragma unroll
    for (int j = 0; j < 16; ++j) t[j] = Wm[q * 33 + h * 16 + j];  // back to rows
  }

  // cost = sum(T*C); C = -lkr/20
  float pp = 0.f;
#pragma unroll
  for (int j = 0; j < 16; ++j) pp = fmaf(t[j], -0.05f * lkr[j], pp);
  pp += __shfl_xor(pp, 1); pp += __shfl_xor(pp, 2); pp += __shfl_xor(pp, 4);
  pp += __shfl_xor(pp, 8); pp += __shfl_xor(pp, 16); pp += __shfl_xor(pp, 32);
  if (lane == 0) {
    costO[p] = pp;
    simO[p] = 1.0f / (1.0f + __expf(pp));  // sigmoid(-cost)
  }
  // T out (coalesced float4 from row view)
#pragma unroll
  for (int jj = 0; jj < 4; ++jj) {
    float4 o;
    o.x = t[jj * 4 + 0]; o.y = t[jj * 4 + 1];
    o.z = t[jj * 4 + 2]; o.w = t[jj * 4 + 3];
    *reinterpret_cast<float4*>(TO + (size_t)p * 1024 + q * 32 + h * 16 + jj * 4) = o;
  }
}

extern "C" void kernel_launch(void* const* d_in, const int* in_sizes, int n_in,
                              void* d_out, int out_size, void* d_ws, size_t ws_size,
                              hipStream_t stream) {
  const float* slots_q = (const float*)d_in[0];
  const float* slots_r = (const float*)d_in[1];
  const float* W1 = (const float*)d_in[2];
  const float* b1 = (const float*)d_in[3];
  const float* W2 = (const float*)d_in[4];
  const float* b2 = (const float*)d_in[5];
  float* out = (float*)d_out;

  const int Bn = in_sizes[0] / 8192;  // 32*256 per batch element
  u16* ws = (u16*)d_ws;               // 256 KB W fragments

  prep_w<<<dim3(512), dim3(256), 0, stream>>>(W1, W2, ws);

  float* simO = out;
  float* TO = out + Bn;
  float* CO = TO + (size_t)Bn * 1024;
  float* costO = CO + (size_t)Bn * 1024;

  gemm_cdist<<<dim3(Bn), dim3(512), 0, stream>>>(slots_q, slots_r, b1, b2, ws, CO);
  sinkhorn_mesh<<<dim3((Bn + 3) / 4), dim3(256), 0, stream>>>(CO, simO, TO, costO, Bn);
}